// Round 2
// baseline (195.000 us; speedup 1.0000x reference)
//
#include <hip/hip_runtime.h>

typedef __bf16 bf16x8 __attribute__((ext_vector_type(8)));
typedef float f32x4 __attribute__((ext_vector_type(4)));
typedef float f32x16 __attribute__((ext_vector_type(16)));
typedef unsigned int u32x4 __attribute__((ext_vector_type(4)));

__device__ inline unsigned short f2bf(float f) {
    unsigned int x = __builtin_bit_cast(unsigned int, f);
    x += 0x7fff + ((x >> 16) & 1);   // RNE; inputs finite
    return (unsigned short)(x >> 16);
}

#if __has_builtin(__builtin_amdgcn_exp2f)
#define EXP2F(x) __builtin_amdgcn_exp2f(x)
#else
#define EXP2F(x) exp2f(x)
#endif

// async global->LDS, 16B per lane; LDS dest = wave-uniform base + lane*16
__device__ __forceinline__ void gl_lds16(const unsigned short* g, unsigned short* l)
{
    __builtin_amdgcn_global_load_lds(
        (const __attribute__((address_space(1))) void*)g,
        (__attribute__((address_space(3))) void*)l, 16, 0, 0);
}

// ---------------------------------------------------------------------------
// Fused prep: blocks [0,2048): x fp32 -> xb bf16 (8 elems/thread).
// Blocks [2048,2816): Wq/Wk/Wv fp32 [k][n] -> wqkvT bf16 [n][k] (64x64 tiles).
// ---------------------------------------------------------------------------
__global__ __launch_bounds__(256)
void prep(const float* __restrict__ x, unsigned short* __restrict__ xb,
          const float* __restrict__ Wq, const float* __restrict__ Wk,
          const float* __restrict__ Wv, unsigned short* __restrict__ wT)
{
    __shared__ unsigned short T[64][72];
    if (blockIdx.x < 2048) {
        const size_t i = ((size_t)blockIdx.x * 256 + threadIdx.x) * 8;
        float4 a = *reinterpret_cast<const float4*>(x + i);
        float4 b = *reinterpret_cast<const float4*>(x + i + 4);
        unsigned short t[8] = { f2bf(a.x), f2bf(a.y), f2bf(a.z), f2bf(a.w),
                                f2bf(b.x), f2bf(b.y), f2bf(b.z), f2bf(b.w) };
        *reinterpret_cast<uint4*>(xb + i) = *reinterpret_cast<uint4*>(t);
        return;
    }
    const int blk = blockIdx.x - 2048;
    const int z = blk >> 8, within = blk & 255;
    const float* W = (z == 0) ? Wq : (z == 1) ? Wk : Wv;
    unsigned short* dstBase = wT + (size_t)z * 1024 * 1024;
    const int k0 = (within >> 4) * 64, n0 = (within & 15) * 64;
    const int r = threadIdx.x >> 2, c0 = (threadIdx.x & 3) * 16;
    const float* src = W + (size_t)(k0 + r) * 1024 + n0 + c0;
    #pragma unroll
    for (int j = 0; j < 16; j += 4) {
        float4 f = *reinterpret_cast<const float4*>(src + j);
        T[r][c0 + j]     = f2bf(f.x);
        T[r][c0 + j + 1] = f2bf(f.y);
        T[r][c0 + j + 2] = f2bf(f.z);
        T[r][c0 + j + 3] = f2bf(f.w);
    }
    __syncthreads();
    unsigned short* dst = dstBase + (size_t)(n0 + r) * 1024 + k0 + c0;
    #pragma unroll
    for (int h = 0; h < 2; ++h) {
        unsigned short t8[8];
        #pragma unroll
        for (int j = 0; j < 8; ++j) t8[j] = T[c0 + h * 8 + j][r];
        *reinterpret_cast<uint4*>(dst + h * 8) = *reinterpret_cast<uint4*>(t8);
    }
}

// ---------------------------------------------------------------------------
// Transpose-convert (Wo): fp32 [k][n] -> bf16 [n][k].
// ---------------------------------------------------------------------------
__global__ __launch_bounds__(256)
void wconv(const float* __restrict__ W, unsigned short* __restrict__ wT)
{
    __shared__ unsigned short T[64][72];
    const int k0 = blockIdx.y * 64, n0 = blockIdx.x * 64;
    const int r = threadIdx.x >> 2, c0 = (threadIdx.x & 3) * 16;
    const float* src = W + (size_t)(k0 + r) * 1024 + n0 + c0;
    #pragma unroll
    for (int j = 0; j < 16; j += 4) {
        float4 f = *reinterpret_cast<const float4*>(src + j);
        T[r][c0 + j]     = f2bf(f.x);
        T[r][c0 + j + 1] = f2bf(f.y);
        T[r][c0 + j + 2] = f2bf(f.z);
        T[r][c0 + j + 3] = f2bf(f.w);
    }
    __syncthreads();
    unsigned short* dst = wT + (size_t)(n0 + r) * 1024 + k0 + c0;
    #pragma unroll
    for (int h = 0; h < 2; ++h) {
        unsigned short t8[8];
        #pragma unroll
        for (int j = 0; j < 8; ++j) t8[j] = T[c0 + h * 8 + j][r];
        *reinterpret_cast<uint4*>(dst + h * 8) = *reinterpret_cast<uint4*>(t8);
    }
}

// ---------------------------------------------------------------------------
// m97-style GEMM: C = A[4096][1024] @ BT[N][1024]^T. 128x128 tile, BK=32,
// unpadded LDS, global_load_lds width-16 staging, 4 waves 2x2, 4x4 mfma.
// MODE 0: QKV routing (q scaled by 0.125*log2e for attn's exp2; k normal,
// v transposed). MODE 2: fp32 out + bias.
// ---------------------------------------------------------------------------
#define QSCALE 0.18033688011112042f   // 0.125 * log2(e)

template <int MODE>
__global__ __launch_bounds__(256)
void gemm128(const unsigned short* __restrict__ A,
             const unsigned short* __restrict__ BT,
             void* __restrict__ C0, void* __restrict__ C1,
             void* __restrict__ C2, const float* __restrict__ bias)
{
    __shared__ unsigned short As[128 * 32];
    __shared__ unsigned short Bs[128 * 32];

    const int tid = threadIdx.x;
    const int wave = tid >> 6, lane = tid & 63, quad = lane >> 4, l16 = lane & 15;
    const int wm = wave >> 1, wn = wave & 1;
    const int mBase = blockIdx.y * 128, nBase = blockIdx.x * 128;

    f32x4 acc[4][4] = {};

    const int srow = lane >> 2, sko = (lane & 3) * 8;

    for (int kb = 0; kb < 1024; kb += 32) {
        __syncthreads();
        #pragma unroll
        for (int j = 0; j < 2; ++j) {
            const int seg = wave * 2 + j;
            gl_lds16(A  + (size_t)(mBase + seg * 16 + srow) * 1024 + kb + sko,
                     As + seg * 512);
            gl_lds16(BT + (size_t)(nBase + seg * 16 + srow) * 1024 + kb + sko,
                     Bs + seg * 512);
        }
        __syncthreads();

        bf16x8 af[4], bf[4];
        #pragma unroll
        for (int t = 0; t < 4; ++t) {
            af[t] = *reinterpret_cast<const bf16x8*>(&As[(wm * 64 + t * 16 + l16) * 32 + quad * 8]);
            bf[t] = *reinterpret_cast<const bf16x8*>(&Bs[(wn * 64 + t * 16 + l16) * 32 + quad * 8]);
        }
        #pragma unroll
        for (int ti = 0; ti < 4; ++ti)
            #pragma unroll
            for (int tj = 0; tj < 4; ++tj)
                acc[ti][tj] = __builtin_amdgcn_mfma_f32_16x16x32_bf16(
                    af[ti], bf[tj], acc[ti][tj], 0, 0, 0);
    }

    #pragma unroll
    for (int ti = 0; ti < 4; ++ti) {
        const int row0 = mBase + wm * 64 + ti * 16 + quad * 4;
        #pragma unroll
        for (int tj = 0; tj < 4; ++tj) {
            const int col = nBase + wn * 64 + tj * 16 + l16;
            if constexpr (MODE == 0) {
                if (col < 1024) {
                    unsigned short* qb = (unsigned short*)C0;
                    #pragma unroll
                    for (int i = 0; i < 4; ++i)
                        qb[(size_t)(row0 + i) * 1024 + col] = f2bf(acc[ti][tj][i] * QSCALE);
                } else if (col < 2048) {
                    unsigned short* kb = (unsigned short*)C1;
                    #pragma unroll
                    for (int i = 0; i < 4; ++i)
                        kb[(size_t)(row0 + i) * 1024 + col - 1024] = f2bf(acc[ti][tj][i]);
                } else {
                    unsigned short* vT = (unsigned short*)C2;
                    unsigned short t4[4] = { f2bf(acc[ti][tj][0]), f2bf(acc[ti][tj][1]),
                                             f2bf(acc[ti][tj][2]), f2bf(acc[ti][tj][3]) };
                    *reinterpret_cast<uint2*>(&vT[(size_t)(col - 2048) * 4096 + row0]) =
                        *reinterpret_cast<uint2*>(t4);
                }
            } else {
                float* out = (float*)C0;
                const float ba = bias[col];
                #pragma unroll
                for (int i = 0; i < 4; ++i)
                    out[(size_t)(row0 + i) * 1024 + col] = acc[ti][tj][i] + ba;
            }
        }
    }
}

// ---------------------------------------------------------------------------
// attn8 = attn7 + T4 deep pipeline: 3-buffer LDS rotation, stage tile kt+2
// each iteration, counted s_waitcnt vmcnt(4) + raw s_barrier (never drain
// vmcnt to 0 in the loop) so one K/V tile stays in flight across each
// barrier (~2 iterations of compute to hide HBM/L2 latency, vs ~0.3 with
// __syncthreads' full drain). Plus: XCD-aware block remap (one (b,h)'s 16
// blocks share an XCD -> 0.5MB K/V L2-resident), Q pre-scaled in gemm so
// softmax uses raw v_exp_f32 (2^x), s_setprio(1) around MFMA clusters.
// Swapped-QK^T in-register softmax + XOR-swizzled staging from attn7.
// ---------------------------------------------------------------------------
__global__ __launch_bounds__(256, 2)
void attn8(const unsigned short* __restrict__ q,
           const unsigned short* __restrict__ k,
           const unsigned short* __restrict__ vT,
           unsigned short* __restrict__ ctx)
{
    __shared__ unsigned short Ks[3][64 * 64];  // [buf][key][d], 16B units XOR-swizzled
    __shared__ unsigned short Vs[3][64 * 64];  // [buf][d][key], 16B units XOR-swizzled
    __shared__ float Lt[8 * 64];               // [wave][tile][lane] l partials

    const int tid  = threadIdx.x;
    const int wave = tid >> 6, lane = tid & 63;
    const int q32 = lane & 31, hi = lane >> 5;
    const int slice = wave & 1;                // 32-row q slice within 64-row macro tile
    const int ks    = wave >> 1;               // 32-key subtile within 64-key staged tile
    // XCD-aware remap: linear dispatch id L -> xcd = L%8 (round-robin); give
    // each XCD 4 whole (b,h) groups so K/V stays in that XCD's L2.
    const int L = (int)(blockIdx.x + (blockIdx.y << 4));
    const int xcd = L & 7, idx = L >> 3;       // idx 0..63
    const int bh = xcd * 4 + (idx >> 4);
    const int j  = idx & 15;                   // 0..15 pair index
    const int b = bh >> 4, h = bh & 15;
    const int tokBase = b * 2048;
    const int colBase = h * 64;
    const int qtA = 31 - j, qtB = j;
    const int qloA = qtA * 64 + slice * 32;    // local (per-batch) q-row base of this wave
    const int qloB = qtB * 64 + slice * 32;

    // Q fragments (QK^T B-operand: lane col q = lane&31, d = c*16 + hi*8 + 0..7)
    bf16x8 aqA[4], aqB[4];
    {
        const unsigned short* ra = q + (size_t)(tokBase + qloA + q32) * 1024 + colBase + hi * 8;
        const unsigned short* rb = q + (size_t)(tokBase + qloB + q32) * 1024 + colBase + hi * 8;
        #pragma unroll
        for (int c = 0; c < 4; ++c) {
            aqA[c] = *reinterpret_cast<const bf16x8*>(ra + c * 16);
            aqB[c] = *reinterpret_cast<const bf16x8*>(rb + c * 16);
        }
    }
    // Force Q materialization here so the compiler's scoreboard wait for these
    // VMEM results lands BEFORE the loop (keeps manual vmcnt accounting exact).
    #pragma unroll
    for (int c = 0; c < 4; ++c)
        asm volatile("" :: "v"(aqA[c]), "v"(aqB[c]));

    f32x16 oA[2] = {}, oB[2] = {};             // [d-half], 32q x 32d each
    float lsA = 0.0f, lsB = 0.0f;

    // Staging: K tile = 64 key-rows x 64 d (128B rows, 8 x 16B units);
    // V tile = 64 d-rows x 64 keys. Linear LDS dest (slot s = r*8 + pu),
    // source pre-swizzled so content at unit pu is logical unit pu ^ (r&7).
    const int s0 = (wave * 2 + 0) * 64 + lane;
    const int s1 = (wave * 2 + 1) * 64 + lane;
    const int r0 = s0 >> 3, sw0 = (s0 & 7) ^ (r0 & 7);
    const int r1 = s1 >> 3, sw1 = (s1 & 7) ^ (r1 & 7);
    const size_t kOff0 = (size_t)r0 * 1024 + colBase + sw0 * 8;
    const size_t kOff1 = (size_t)r1 * 1024 + colBase + sw1 * 8;
    const size_t vOff0 = (size_t)(colBase + r0) * 4096 + sw0 * 8;
    const size_t vOff1 = (size_t)(colBase + r1) * 4096 + sw1 * 8;

    auto stage = [&](int tok0, int buf) {
        gl_lds16(k  + (size_t)tok0 * 1024 + kOff0, &Ks[buf][(wave * 2 + 0) * 512]);
        gl_lds16(k  + (size_t)tok0 * 1024 + kOff1, &Ks[buf][(wave * 2 + 1) * 512]);
        gl_lds16(vT + vOff0 + tok0,                &Vs[buf][(wave * 2 + 0) * 512]);
        gl_lds16(vT + vOff1 + tok0,                &Vs[buf][(wave * 2 + 1) * 512]);
    };

    bf16x8 ak[4];       // K frags (shared by tiles A and B)
    bf16x8 bv[2][2];    // V frags [k-chunk][d-half] (shared by A and B)

    // One (q,k) 32x32 tile: swapped QK^T -> in-register softmax -> PV.
    auto tile = [&](const bf16x8 (&aq)[4], f32x16 (&o)[2], float& ls,
                    int qlo, int klo) {
        if (klo > qlo + 31) return;                      // fully masked (wave-uniform)
        f32x16 sc = (f32x16)0.0f;
        __builtin_amdgcn_s_setprio(1);
        #pragma unroll
        for (int c = 0; c < 4; ++c)
            sc = __builtin_amdgcn_mfma_f32_32x32x16_bf16(ak[c], aq[c], sc, 0, 0, 0);
        __builtin_amdgcn_s_setprio(0);
        // lane holds S[k = klo + krow(r,hi)][q = qlo + q32]; Q pre-scaled, exp2
        float p[16];
        #pragma unroll
        for (int r = 0; r < 16; ++r) p[r] = EXP2F(sc[r]);
        if (klo + 31 > qlo) {                            // diagonal block: causal mask
            #pragma unroll
            for (int r = 0; r < 16; ++r) {
                const int krow = (r & 3) + 8 * (r >> 2) + 4 * hi;
                if (klo + krow > qlo + q32) p[r] = 0.0f;
            }
        }
        #pragma unroll
        for (int r = 0; r < 16; ++r) ls += p[r];
        // pack consecutive-k pairs to bf16 (8 words)
        unsigned int pk[8];
        #pragma unroll
        for (int i = 0; i < 8; ++i)
            asm("v_cvt_pk_bf16_f32 %0, %1, %2"
                : "=v"(pk[i]) : "v"(p[2 * i]), "v"(p[2 * i + 1]));
        // build PV A-frags: swap(pk[i], pk[i+2]) fills words i and i+2 of both halves
        #pragma unroll
        for (int kc = 0; kc < 2; ++kc) {
            unsigned int x0 = pk[kc * 4 + 0], y0 = pk[kc * 4 + 2];
            unsigned int x1 = pk[kc * 4 + 1], y1 = pk[kc * 4 + 3];
            asm("v_permlane32_swap_b32 %0, %1" : "+v"(x0), "+v"(y0));
            asm("v_permlane32_swap_b32 %0, %1" : "+v"(x1), "+v"(y1));
            const u32x4 wv = { x0, x1, y0, y1 };
            const bf16x8 pa = __builtin_bit_cast(bf16x8, wv);
            __builtin_amdgcn_s_setprio(1);
            #pragma unroll
            for (int dh = 0; dh < 2; ++dh)
                o[dh] = __builtin_amdgcn_mfma_f32_32x32x16_bf16(pa, bv[kc][dh], o[dh], 0, 0, 0);
            __builtin_amdgcn_s_setprio(0);
        }
    };

    const int nkt = qtA + 1;                   // 64-key tiles; >= 17 always
    stage(tokBase, 0);                         // prologue: 2 tiles in flight
    stage(tokBase + 64, 1);

    int cur = 0;                               // buffer holding tile kt
    const int krowK = ks * 32 + q32;           // K-frag LDS row for this wave
    for (int kt = 0; kt < nkt; ++kt) {
        // retire tile kt's 4 loads; leave tile kt+1's 4 in flight (T4)
        if (kt + 1 < nkt) asm volatile("s_waitcnt vmcnt(4)" ::: "memory");
        else              asm volatile("s_waitcnt vmcnt(0)" ::: "memory");
        __builtin_amdgcn_s_barrier();
        asm volatile("" ::: "memory");
        const int stg = (cur == 0) ? 2 : cur - 1;        // (cur+2)%3
        if (kt + 2 < nkt)
            stage(tokBase + (kt + 2) * 64, stg);         // lands ~2 iters from now
        const unsigned short* KsB = Ks[cur];
        const unsigned short* VsB = Vs[cur];
        #pragma unroll
        for (int c = 0; c < 4; ++c) {
            const int u = c * 2 + hi;
            ak[c] = *reinterpret_cast<const bf16x8*>(
                &KsB[krowK * 64 + ((u ^ (krowK & 7)) * 8)]);
        }
        #pragma unroll
        for (int kc = 0; kc < 2; ++kc)
            #pragma unroll
            for (int dh = 0; dh < 2; ++dh) {
                const int vrow = dh * 32 + q32;
                const int u = ks * 4 + kc * 2 + hi;
                bv[kc][dh] = *reinterpret_cast<const bf16x8*>(
                    &VsB[vrow * 64 + ((u ^ (vrow & 7)) * 8)]);
            }
        const int klo = kt * 64 + ks * 32;
        tile(aqA, oA, lsA, qloA, klo);
        tile(aqB, oB, lsB, qloB, klo);
        cur = (cur == 2) ? 0 : cur + 1;
    }

    // ---- epilogue: combine the two k-subtile partials per q-slice, normalize
    float* Obuf = reinterpret_cast<float*>(&Ks[0][0]);   // 2 slots x 8KB (overlay)

    __syncthreads();                           // all compute reads done; overlay safe
    Lt[(wave * 2 + 0) * 64 + lane] = lsA;
    Lt[(wave * 2 + 1) * 64 + lane] = lsB;

    auto writePartial = [&](const f32x16 (&o)[2]) {
        float* slot = Obuf + slice * 2048;
        #pragma unroll
        for (int r = 0; r < 16; ++r) {
            const int row = (r & 3) + 8 * (r >> 2) + 4 * hi;
            #pragma unroll
            for (int dh = 0; dh < 2; ++dh)
                slot[row * 64 + dh * 32 + q32] = o[dh][r];
        }
    };
    auto finalize = [&](int t, int qt, const f32x16 (&o)[2]) {
        const float lf = Lt[(slice * 2 + t) * 64 + q32]
                       + Lt[(slice * 2 + t) * 64 + 32 + q32]
                       + Lt[((slice + 2) * 2 + t) * 64 + q32]
                       + Lt[((slice + 2) * 2 + t) * 64 + 32 + q32];
        const float inv = 1.0f / lf;
        const float* slot = Obuf + slice * 2048;
        #pragma unroll
        for (int r = 0; r < 16; ++r) {
            const int row = (r & 3) + 8 * (r >> 2) + 4 * hi;
            const float invr = __shfl(inv, row);
            const size_t gr = (size_t)(tokBase + qt * 64 + slice * 32 + row) * 1024 + colBase;
            #pragma unroll
            for (int dh = 0; dh < 2; ++dh)
                ctx[gr + dh * 32 + q32] =
                    f2bf((o[dh][r] + slot[row * 64 + dh * 32 + q32]) * invr);
        }
    };

    if (ks == 1) writePartial(oA);             // waves 2,3 publish A partials
    __syncthreads();
    if (ks == 0) finalize(0, qtA, oA);         // waves 0,1 finalize tile A
    __syncthreads();
    if (ks == 0) writePartial(oB);             // waves 0,1 publish B partials
    __syncthreads();
    if (ks == 1) finalize(1, qtB, oB);         // waves 2,3 finalize tile B
}

// ---------------------------------------------------------------------------
extern "C" void kernel_launch(void* const* d_in, const int* in_sizes, int n_in,
                              void* d_out, int out_size, void* d_ws, size_t ws_size,
                              hipStream_t stream)
{
    const float* x  = (const float*)d_in[0];   // [4096,1024] fp32
    const float* Wq = (const float*)d_in[1];
    const float* Wk = (const float*)d_in[2];
    const float* Wv = (const float*)d_in[3];
    const float* Wo = (const float*)d_in[4];
    const float* bo = (const float*)d_in[5];
    float* out = (float*)d_out;

    // ws (32 MB): xb -> ctx after gemm_qkv; kb -> woT after attn.
    // d_out doubles as wqkvT scratch until gemm_out overwrites it.
    unsigned short* xb     = (unsigned short*)d_ws;           // 8 MB -> ctx
    unsigned short* qb     = xb + (size_t)4096 * 1024;        // 8 MB
    unsigned short* kb     = qb + (size_t)4096 * 1024;        // 8 MB -> woT
    unsigned short* vT     = kb + (size_t)4096 * 1024;        // 8 MB [1024][4096]
    unsigned short* ctx    = xb;
    unsigned short* wqkvT  = (unsigned short*)d_out;          // 6.3 MB scratch
    unsigned short* woT    = kb;

    prep<<<2816, 256, 0, stream>>>(x, xb, Wq, Wk, Wv, wqkvT);

    gemm128<0><<<dim3(24, 32), 256, 0, stream>>>(xb, wqkvT, qb, kb, vT, nullptr);

    attn8<<<dim3(16, 32), 256, 0, stream>>>(qb, kb, vT, ctx);

    wconv<<<dim3(16, 16), 256, 0, stream>>>(Wo, woT);

    gemm128<2><<<dim3(8, 32), 256, 0, stream>>>(ctx, woT, out, nullptr, nullptr, bo);
}

// Round 3
// 193.838 us; speedup vs baseline: 1.0060x; 1.0060x over previous
//
#include <hip/hip_runtime.h>

typedef __bf16 bf16x8 __attribute__((ext_vector_type(8)));
typedef float f32x4 __attribute__((ext_vector_type(4)));
typedef float f32x16 __attribute__((ext_vector_type(16)));
typedef unsigned int u32x4 __attribute__((ext_vector_type(4)));

__device__ inline unsigned short f2bf(float f) {
    unsigned int x = __builtin_bit_cast(unsigned int, f);
    x += 0x7fff + ((x >> 16) & 1);   // RNE; inputs finite
    return (unsigned short)(x >> 16);
}

// async global->LDS, 16B per lane; LDS dest = wave-uniform base + lane*16
__device__ __forceinline__ void gl_lds16(const unsigned short* g, unsigned short* l)
{
    __builtin_amdgcn_global_load_lds(
        (const __attribute__((address_space(1))) void*)g,
        (__attribute__((address_space(3))) void*)l, 16, 0, 0);
}

// ---------------------------------------------------------------------------
// Fused prep: blocks [0,2048): x fp32 -> xb bf16 (8 elems/thread).
// Blocks [2048,2816): Wq/Wk/Wv fp32 [k][n] -> wqkvT bf16 [n][k] (64x64 tiles).
// ---------------------------------------------------------------------------
__global__ __launch_bounds__(256)
void prep(const float* __restrict__ x, unsigned short* __restrict__ xb,
          const float* __restrict__ Wq, const float* __restrict__ Wk,
          const float* __restrict__ Wv, unsigned short* __restrict__ wT)
{
    __shared__ unsigned short T[64][72];
    if (blockIdx.x < 2048) {
        const size_t i = ((size_t)blockIdx.x * 256 + threadIdx.x) * 8;
        float4 a = *reinterpret_cast<const float4*>(x + i);
        float4 b = *reinterpret_cast<const float4*>(x + i + 4);
        unsigned short t[8] = { f2bf(a.x), f2bf(a.y), f2bf(a.z), f2bf(a.w),
                                f2bf(b.x), f2bf(b.y), f2bf(b.z), f2bf(b.w) };
        *reinterpret_cast<uint4*>(xb + i) = *reinterpret_cast<uint4*>(t);
        return;
    }
    const int blk = blockIdx.x - 2048;
    const int z = blk >> 8, within = blk & 255;
    const float* W = (z == 0) ? Wq : (z == 1) ? Wk : Wv;
    unsigned short* dstBase = wT + (size_t)z * 1024 * 1024;
    const int k0 = (within >> 4) * 64, n0 = (within & 15) * 64;
    const int r = threadIdx.x >> 2, c0 = (threadIdx.x & 3) * 16;
    const float* src = W + (size_t)(k0 + r) * 1024 + n0 + c0;
    #pragma unroll
    for (int j = 0; j < 16; j += 4) {
        float4 f = *reinterpret_cast<const float4*>(src + j);
        T[r][c0 + j]     = f2bf(f.x);
        T[r][c0 + j + 1] = f2bf(f.y);
        T[r][c0 + j + 2] = f2bf(f.z);
        T[r][c0 + j + 3] = f2bf(f.w);
    }
    __syncthreads();
    unsigned short* dst = dstBase + (size_t)(n0 + r) * 1024 + k0 + c0;
    #pragma unroll
    for (int h = 0; h < 2; ++h) {
        unsigned short t8[8];
        #pragma unroll
        for (int j = 0; j < 8; ++j) t8[j] = T[c0 + h * 8 + j][r];
        *reinterpret_cast<uint4*>(dst + h * 8) = *reinterpret_cast<uint4*>(t8);
    }
}

// ---------------------------------------------------------------------------
// Transpose-convert (Wo): fp32 [k][n] -> bf16 [n][k].
// ---------------------------------------------------------------------------
__global__ __launch_bounds__(256)
void wconv(const float* __restrict__ W, unsigned short* __restrict__ wT)
{
    __shared__ unsigned short T[64][72];
    const int k0 = blockIdx.y * 64, n0 = blockIdx.x * 64;
    const int r = threadIdx.x >> 2, c0 = (threadIdx.x & 3) * 16;
    const float* src = W + (size_t)(k0 + r) * 1024 + n0 + c0;
    #pragma unroll
    for (int j = 0; j < 16; j += 4) {
        float4 f = *reinterpret_cast<const float4*>(src + j);
        T[r][c0 + j]     = f2bf(f.x);
        T[r][c0 + j + 1] = f2bf(f.y);
        T[r][c0 + j + 2] = f2bf(f.z);
        T[r][c0 + j + 3] = f2bf(f.w);
    }
    __syncthreads();
    unsigned short* dst = wT + (size_t)(n0 + r) * 1024 + k0 + c0;
    #pragma unroll
    for (int h = 0; h < 2; ++h) {
        unsigned short t8[8];
        #pragma unroll
        for (int j = 0; j < 8; ++j) t8[j] = T[c0 + h * 8 + j][r];
        *reinterpret_cast<uint4*>(dst + h * 8) = *reinterpret_cast<uint4*>(t8);
    }
}

// ---------------------------------------------------------------------------
// gemm256: QKV projection C = A[4096][1024] @ BT[3072][1024]^T with q/k/v
// routing. 256x192 tile -> grid 16x16 = 256 blocks = exactly 1 block/CU.
// 512 threads = 8 waves (2M x 4N), per-wave output 128x48 (acc[8][3]).
// BK=32, THREE LDS sets rotated: stage(t+2) issued at iter t, counted
// s_waitcnt vmcnt(Lw) + raw s_barrier per K-step (never drain to 0 in the
// loop) -> ~2 iterations of MFMA to hide staging latency (T4).
// LDS frag reads XOR-swizzled (physical 16B unit = quad ^ ((row>>2)&3)),
// applied on the global_load_lds SOURCE address (linear LDS dest, rule #21):
// turns the 8-way bank conflict of unpadded 64B rows into a free 2-way.
// WAR safety: set (t+2)%3 overwritten at iter t was last read at iter t-1;
// all waves' iter-(t-1) ds_reads complete before their iter-t barrier entry.
// ---------------------------------------------------------------------------
__global__ __launch_bounds__(512, 2)
void gemm256(const unsigned short* __restrict__ A,
             const unsigned short* __restrict__ BT,
             unsigned short* __restrict__ qb,
             unsigned short* __restrict__ kb,
             unsigned short* __restrict__ vT)
{
    __shared__ unsigned short AsB[3][256 * 32];   // 3 x 16 KB
    __shared__ unsigned short BsB[3][192 * 32];   // 3 x 12 KB

    const int tid  = threadIdx.x;
    const int wave = tid >> 6, lane = tid & 63;
    const int quad = lane >> 4, l16 = lane & 15;
    const int wm = wave >> 2, wn = wave & 3;      // 2 x 4 wave grid
    const int mBase = blockIdx.y * 256, nBase = blockIdx.x * 192;

    f32x4 acc[8][3] = {};

    // Staging geometry: tile rows of 32 bf16 = 4 x 16B units. Unit s of a
    // wave-load covers LDS row r = s>>2, physical unit pu = s&3; the content
    // fetched is logical unit u = pu ^ ((r>>2)&3). Per lane both reduce to
    // lane-only expressions (i*16 contributions vanish mod 4):
    const int slane = lane >> 2;                       // row-within-16
    const int su    = (lane & 3) ^ ((lane >> 4) & 3);  // logical k-unit 0..3
    const int physq = quad ^ (l16 >> 2);               // read-side swizzle

    // A: 16 wave-loads (2/wave). B: 12 wave-loads (waves 0-3: 2, waves 4-7: 1).
    auto stage = [&](int kb0, unsigned short* As, unsigned short* Bs) {
        #pragma unroll
        for (int c = 0; c < 2; ++c) {
            const int i = wave * 2 + c;
            gl_lds16(A + (size_t)(mBase + i * 16 + slane) * 1024 + kb0 + su * 8,
                     As + i * 512);
        }
        if (wave < 4) {
            #pragma unroll
            for (int c = 0; c < 2; ++c) {
                const int jj = wave * 2 + c;
                gl_lds16(BT + (size_t)(nBase + jj * 16 + slane) * 1024 + kb0 + su * 8,
                         Bs + jj * 512);
            }
        } else {
            const int jj = 8 + (wave - 4);
            gl_lds16(BT + (size_t)(nBase + jj * 16 + slane) * 1024 + kb0 + su * 8,
                     Bs + jj * 512);
        }
    };

    stage(0,  AsB[0], BsB[0]);     // prologue: 2 K-tiles in flight
    stage(32, AsB[1], BsB[1]);

    int cur = 0;                   // set holding K-tile t
    for (int t = 0; t < 32; ++t) {
        // retire tile t's own loads; leave tile t+1's in flight (T4)
        if (t + 1 < 32) {
            if (wave < 4) asm volatile("s_waitcnt vmcnt(4)" ::: "memory");
            else          asm volatile("s_waitcnt vmcnt(3)" ::: "memory");
        } else {
            asm volatile("s_waitcnt vmcnt(0)" ::: "memory");
        }
        __builtin_amdgcn_s_barrier();
        asm volatile("" ::: "memory");

        const int nxt = (cur == 0) ? 2 : cur - 1;      // (cur+2)%3
        if (t + 2 < 32)
            stage((t + 2) * 32, AsB[nxt], BsB[nxt]);   // lands ~2 iters out

        const unsigned short* As = AsB[cur];
        const unsigned short* Bs = BsB[cur];
        bf16x8 af[8], bf[3];
        #pragma unroll
        for (int mr = 0; mr < 8; ++mr) {
            const int row = wm * 128 + mr * 16 + l16;
            af[mr] = *reinterpret_cast<const bf16x8*>(&As[row * 32 + physq * 8]);
        }
        #pragma unroll
        for (int nr = 0; nr < 3; ++nr) {
            const int row = wn * 48 + nr * 16 + l16;
            bf[nr] = *reinterpret_cast<const bf16x8*>(&Bs[row * 32 + physq * 8]);
        }
        #pragma unroll
        for (int mr = 0; mr < 8; ++mr)
            #pragma unroll
            for (int nr = 0; nr < 3; ++nr)
                acc[mr][nr] = __builtin_amdgcn_mfma_f32_16x16x32_bf16(
                    af[mr], bf[nr], acc[mr][nr], 0, 0, 0);

        cur = (cur == 2) ? 0 : cur + 1;
    }

    // ---- epilogue: q/k normal, v transposed
    #pragma unroll
    for (int mr = 0; mr < 8; ++mr) {
        const int row0 = mBase + wm * 128 + mr * 16 + quad * 4;
        #pragma unroll
        for (int nr = 0; nr < 3; ++nr) {
            const int col = nBase + wn * 48 + nr * 16 + l16;
            if (col < 1024) {
                #pragma unroll
                for (int i = 0; i < 4; ++i)
                    qb[(size_t)(row0 + i) * 1024 + col] = f2bf(acc[mr][nr][i]);
            } else if (col < 2048) {
                #pragma unroll
                for (int i = 0; i < 4; ++i)
                    kb[(size_t)(row0 + i) * 1024 + col - 1024] = f2bf(acc[mr][nr][i]);
            } else {
                unsigned short t4[4] = { f2bf(acc[mr][nr][0]), f2bf(acc[mr][nr][1]),
                                         f2bf(acc[mr][nr][2]), f2bf(acc[mr][nr][3]) };
                *reinterpret_cast<uint2*>(&vT[(size_t)(col - 2048) * 4096 + row0]) =
                    *reinterpret_cast<uint2*>(t4);
            }
        }
    }
}

// ---------------------------------------------------------------------------
// m97-style GEMM (out-projection only): C = A @ BT^T, fp32 out + bias.
// ---------------------------------------------------------------------------
template <int MODE>
__global__ __launch_bounds__(256)
void gemm128(const unsigned short* __restrict__ A,
             const unsigned short* __restrict__ BT,
             void* __restrict__ C0, void* __restrict__ C1,
             void* __restrict__ C2, const float* __restrict__ bias)
{
    __shared__ unsigned short As[128 * 32];
    __shared__ unsigned short Bs[128 * 32];

    const int tid = threadIdx.x;
    const int wave = tid >> 6, lane = tid & 63, quad = lane >> 4, l16 = lane & 15;
    const int wm = wave >> 1, wn = wave & 1;
    const int mBase = blockIdx.y * 128, nBase = blockIdx.x * 128;

    f32x4 acc[4][4] = {};

    const int srow = lane >> 2, sko = (lane & 3) * 8;

    for (int kb = 0; kb < 1024; kb += 32) {
        __syncthreads();
        #pragma unroll
        for (int j = 0; j < 2; ++j) {
            const int seg = wave * 2 + j;
            gl_lds16(A  + (size_t)(mBase + seg * 16 + srow) * 1024 + kb + sko,
                     As + seg * 512);
            gl_lds16(BT + (size_t)(nBase + seg * 16 + srow) * 1024 + kb + sko,
                     Bs + seg * 512);
        }
        __syncthreads();

        bf16x8 af[4], bf[4];
        #pragma unroll
        for (int t = 0; t < 4; ++t) {
            af[t] = *reinterpret_cast<const bf16x8*>(&As[(wm * 64 + t * 16 + l16) * 32 + quad * 8]);
            bf[t] = *reinterpret_cast<const bf16x8*>(&Bs[(wn * 64 + t * 16 + l16) * 32 + quad * 8]);
        }
        #pragma unroll
        for (int ti = 0; ti < 4; ++ti)
            #pragma unroll
            for (int tj = 0; tj < 4; ++tj)
                acc[ti][tj] = __builtin_amdgcn_mfma_f32_16x16x32_bf16(
                    af[ti], bf[tj], acc[ti][tj], 0, 0, 0);
    }

    #pragma unroll
    for (int ti = 0; ti < 4; ++ti) {
        const int row0 = mBase + wm * 64 + ti * 16 + quad * 4;
        #pragma unroll
        for (int tj = 0; tj < 4; ++tj) {
            const int col = nBase + wn * 64 + tj * 16 + l16;
            float* out = (float*)C0;
            const float ba = bias[col];
            #pragma unroll
            for (int i = 0; i < 4; ++i)
                out[(size_t)(row0 + i) * 1024 + col] = acc[ti][tj][i] + ba;
        }
    }
}

// ---------------------------------------------------------------------------
// MFMA causal flash attention attn7 (r1-verified): swapped-QK^T 32x32x16,
// fully in-register softmax (T12), conflict-free XOR-swizzled K/V staging
// (T2 via pre-swizzled global_load_lds source). Triangle folding: block j
// owns q-macro-tiles (31-j, j), 33 equal iterations. 4 waves = (q-slice x
// k-subtile); scores land q = lane&31, k in-register -> softmax l is one
// scalar/lane, P->bf16 via v_cvt_pk_bf16_f32, PV A-frags built with
// v_permlane32_swap_b32. Partial O/l combine linearly via LDS epilogue.
// ---------------------------------------------------------------------------
__global__ __launch_bounds__(256, 2)
void attn7(const unsigned short* __restrict__ q,
           const unsigned short* __restrict__ k,
           const unsigned short* __restrict__ vT,
           unsigned short* __restrict__ ctx)
{
    __shared__ unsigned short Ks[2][64 * 64];  // [buf][key][d], 16B units XOR-swizzled
    __shared__ unsigned short Vs[2][64 * 64];  // [buf][d][key], 16B units XOR-swizzled
    __shared__ float Lt[8 * 64];               // [wave][tile][lane] l partials

    const int tid  = threadIdx.x;
    const int wave = tid >> 6, lane = tid & 63;
    const int q32 = lane & 31, hi = lane >> 5;
    const int slice = wave & 1;                // 32-row q slice within 64-row macro tile
    const int ks    = wave >> 1;               // 32-key subtile within 64-key staged tile
    const int j  = blockIdx.x;                 // 0..15 pair index
    const int bh = blockIdx.y;
    const int b = bh >> 4, h = bh & 15;
    const int tokBase = b * 2048;
    const int colBase = h * 64;
    const int qtA = 31 - j, qtB = j;
    const int qloA = qtA * 64 + slice * 32;    // local (per-batch) q-row base of this wave
    const int qloB = qtB * 64 + slice * 32;

    // Q fragments (QK^T B-operand: lane col q = lane&31, d = c*16 + hi*8 + 0..7)
    bf16x8 aqA[4], aqB[4];
    {
        const unsigned short* ra = q + (size_t)(tokBase + qloA + q32) * 1024 + colBase + hi * 8;
        const unsigned short* rb = q + (size_t)(tokBase + qloB + q32) * 1024 + colBase + hi * 8;
        #pragma unroll
        for (int c = 0; c < 4; ++c) {
            aqA[c] = *reinterpret_cast<const bf16x8*>(ra + c * 16);
            aqB[c] = *reinterpret_cast<const bf16x8*>(rb + c * 16);
        }
    }

    f32x16 oA[2] = {}, oB[2] = {};             // [d-half], 32q x 32d each
    float lsA = 0.0f, lsB = 0.0f;

    // Staging: K tile = 64 key-rows x 64 d (128B rows, 8 x 16B units);
    // V tile = 64 d-rows x 64 keys. Linear LDS dest (slot s = r*8 + pu),
    // source pre-swizzled so content at unit pu is logical unit pu ^ (r&7).
    const int s0 = (wave * 2 + 0) * 64 + lane;
    const int s1 = (wave * 2 + 1) * 64 + lane;
    const int r0 = s0 >> 3, sw0 = (s0 & 7) ^ (r0 & 7);
    const int r1 = s1 >> 3, sw1 = (s1 & 7) ^ (r1 & 7);
    const size_t kOff0 = (size_t)r0 * 1024 + colBase + sw0 * 8;
    const size_t kOff1 = (size_t)r1 * 1024 + colBase + sw1 * 8;
    const size_t vOff0 = (size_t)(colBase + r0) * 4096 + sw0 * 8;
    const size_t vOff1 = (size_t)(colBase + r1) * 4096 + sw1 * 8;

    auto stage = [&](int tok0, int buf) {
        gl_lds16(k  + (size_t)tok0 * 1024 + kOff0, &Ks[buf][(wave * 2 + 0) * 512]);
        gl_lds16(k  + (size_t)tok0 * 1024 + kOff1, &Ks[buf][(wave * 2 + 1) * 512]);
        gl_lds16(vT + vOff0 + tok0,                &Vs[buf][(wave * 2 + 0) * 512]);
        gl_lds16(vT + vOff1 + tok0,                &Vs[buf][(wave * 2 + 1) * 512]);
    };

    bf16x8 ak[4];       // K frags (shared by tiles A and B)
    bf16x8 bv[2][2];    // V frags [k-chunk][d-half] (shared by A and B)

    // One (q,k) 32x32 tile: swapped QK^T -> in-register softmax -> PV.
    auto tile = [&](const bf16x8 (&aq)[4], f32x16 (&o)[2], float& ls,
                    int qlo, int klo) {
        if (klo > qlo + 31) return;                      // fully masked (wave-uniform)
        f32x16 sc = (f32x16)0.0f;
        #pragma unroll
        for (int c = 0; c < 4; ++c)
            sc = __builtin_amdgcn_mfma_f32_32x32x16_bf16(ak[c], aq[c], sc, 0, 0, 0);
        // lane holds S[k = klo + krow(r,hi)][q = qlo + q32]
        float p[16];
        #pragma unroll
        for (int r = 0; r < 16; ++r) p[r] = __expf(sc[r] * 0.125f);
        if (klo + 31 > qlo) {                            // diagonal block: causal mask
            #pragma unroll
            for (int r = 0; r < 16; ++r) {
                const int krow = (r & 3) + 8 * (r >> 2) + 4 * hi;
                if (klo + krow > qlo + q32) p[r] = 0.0f;
            }
        }
        #pragma unroll
        for (int r = 0; r < 16; ++r) ls += p[r];
        // pack consecutive-k pairs to bf16 (8 words)
        unsigned int pk[8];
        #pragma unroll
        for (int i = 0; i < 8; ++i)
            asm("v_cvt_pk_bf16_f32 %0, %1, %2"
                : "=v"(pk[i]) : "v"(p[2 * i]), "v"(p[2 * i + 1]));
        // build PV A-frags: swap(pk[i], pk[i+2]) fills words i and i+2 of both halves
        #pragma unroll
        for (int kc = 0; kc < 2; ++kc) {
            unsigned int x0 = pk[kc * 4 + 0], y0 = pk[kc * 4 + 2];
            unsigned int x1 = pk[kc * 4 + 1], y1 = pk[kc * 4 + 3];
            asm("v_permlane32_swap_b32 %0, %1" : "+v"(x0), "+v"(y0));
            asm("v_permlane32_swap_b32 %0, %1" : "+v"(x1), "+v"(y1));
            const u32x4 wv = { x0, x1, y0, y1 };
            const bf16x8 pa = __builtin_bit_cast(bf16x8, wv);
            #pragma unroll
            for (int dh = 0; dh < 2; ++dh)
                o[dh] = __builtin_amdgcn_mfma_f32_32x32x16_bf16(pa, bv[kc][dh], o[dh], 0, 0, 0);
        }
    };

    stage(tokBase, 0);
    __syncthreads();                           // drains tile-0 DMA

    const int nkt = qtA + 1;                   // 64-key tiles (tile A's range)
    int buf = 0;
    const int krowK = ks * 32 + q32;           // K-frag LDS row for this wave
    for (int kt = 0; kt < nkt; ++kt) {
        if (kt + 1 < nkt)
            stage(tokBase + (kt + 1) * 64, buf ^ 1);     // async, lands by barrier
        const unsigned short* KsB = Ks[buf];
        const unsigned short* VsB = Vs[buf];
        #pragma unroll
        for (int c = 0; c < 4; ++c) {
            const int u = c * 2 + hi;
            ak[c] = *reinterpret_cast<const bf16x8*>(
                &KsB[krowK * 64 + ((u ^ (krowK & 7)) * 8)]);
        }
        #pragma unroll
        for (int kc = 0; kc < 2; ++kc)
            #pragma unroll
            for (int dh = 0; dh < 2; ++dh) {
                const int vrow = dh * 32 + q32;
                const int u = ks * 4 + kc * 2 + hi;
                bv[kc][dh] = *reinterpret_cast<const bf16x8*>(
                    &VsB[vrow * 64 + ((u ^ (vrow & 7)) * 8)]);
            }
        const int klo = kt * 64 + ks * 32;
        tile(aqA, oA, lsA, qloA, klo);
        tile(aqB, oB, lsB, qloB, klo);
        if (kt + 1 < nkt)
            __syncthreads();                   // drains prefetch; guards buffer swap
        buf ^= 1;
    }

    // ---- epilogue: combine the two k-subtile partials per q-slice, normalize
    float* Obuf = reinterpret_cast<float*>(&Ks[0][0]);   // 2 slots x 8KB (overlay)

    __syncthreads();                           // all compute reads done; overlay safe
    Lt[(wave * 2 + 0) * 64 + lane] = lsA;
    Lt[(wave * 2 + 1) * 64 + lane] = lsB;

    auto writePartial = [&](const f32x16 (&o)[2]) {
        float* slot = Obuf + slice * 2048;
        #pragma unroll
        for (int r = 0; r < 16; ++r) {
            const int row = (r & 3) + 8 * (r >> 2) + 4 * hi;
            #pragma unroll
            for (int dh = 0; dh < 2; ++dh)
                slot[row * 64 + dh * 32 + q32] = o[dh][r];
        }
    };
    auto finalize = [&](int t, int qt, const f32x16 (&o)[2]) {
        const float lf = Lt[(slice * 2 + t) * 64 + q32]
                       + Lt[(slice * 2 + t) * 64 + 32 + q32]
                       + Lt[((slice + 2) * 2 + t) * 64 + q32]
                       + Lt[((slice + 2) * 2 + t) * 64 + 32 + q32];
        const float inv = 1.0f / lf;
        const float* slot = Obuf + slice * 2048;
        #pragma unroll
        for (int r = 0; r < 16; ++r) {
            const int row = (r & 3) + 8 * (r >> 2) + 4 * hi;
            const float invr = __shfl(inv, row);
            const size_t gr = (size_t)(tokBase + qt * 64 + slice * 32 + row) * 1024 + colBase;
            #pragma unroll
            for (int dh = 0; dh < 2; ++dh)
                ctx[gr + dh * 32 + q32] =
                    f2bf((o[dh][r] + slot[row * 64 + dh * 32 + q32]) * invr);
        }
    };

    if (ks == 1) writePartial(oA);             // waves 2,3 publish A partials
    __syncthreads();
    if (ks == 0) finalize(0, qtA, oA);         // waves 0,1 finalize tile A
    __syncthreads();
    if (ks == 0) writePartial(oB);             // waves 0,1 publish B partials
    __syncthreads();
    if (ks == 1) finalize(1, qtB, oB);         // waves 2,3 finalize tile B
}

// ---------------------------------------------------------------------------
extern "C" void kernel_launch(void* const* d_in, const int* in_sizes, int n_in,
                              void* d_out, int out_size, void* d_ws, size_t ws_size,
                              hipStream_t stream)
{
    const float* x  = (const float*)d_in[0];   // [4096,1024] fp32
    const float* Wq = (const float*)d_in[1];
    const float* Wk = (const float*)d_in[2];
    const float* Wv = (const float*)d_in[3];
    const float* Wo = (const float*)d_in[4];
    const float* bo = (const float*)d_in[5];
    float* out = (float*)d_out;

    // ws (32 MB): xb -> ctx after gemm_qkv; kb -> woT after attn.
    // d_out doubles as wqkvT scratch until gemm_out overwrites it.
    unsigned short* xb     = (unsigned short*)d_ws;           // 8 MB -> ctx
    unsigned short* qb     = xb + (size_t)4096 * 1024;        // 8 MB
    unsigned short* kb     = qb + (size_t)4096 * 1024;        // 8 MB -> woT
    unsigned short* vT     = kb + (size_t)4096 * 1024;        // 8 MB [1024][4096]
    unsigned short* ctx    = xb;
    unsigned short* wqkvT  = (unsigned short*)d_out;          // 6.3 MB scratch
    unsigned short* woT    = kb;

    prep<<<2816, 256, 0, stream>>>(x, xb, Wq, Wk, Wv, wqkvT);

    gemm256<<<dim3(16, 16), 512, 0, stream>>>(xb, wqkvT, qb, kb, vT);

    attn7<<<dim3(16, 32), 256, 0, stream>>>(qb, kb, vT, ctx);

    wconv<<<dim3(16, 16), 256, 0, stream>>>(Wo, woT);

    gemm128<2><<<dim3(8, 32), 256, 0, stream>>>(ctx, woT, out, nullptr, nullptr, bo);
}

// Round 4
// 183.266 us; speedup vs baseline: 1.0640x; 1.0577x over previous
//
#include <hip/hip_runtime.h>

typedef __bf16 bf16x8 __attribute__((ext_vector_type(8)));
typedef float f32x4 __attribute__((ext_vector_type(4)));
typedef float f32x16 __attribute__((ext_vector_type(16)));
typedef unsigned int u32x4 __attribute__((ext_vector_type(4)));

__device__ inline unsigned short f2bf(float f) {
    unsigned int x = __builtin_bit_cast(unsigned int, f);
    x += 0x7fff + ((x >> 16) & 1);   // RNE; inputs finite
    return (unsigned short)(x >> 16);
}

// async global->LDS, 16B per lane; LDS dest = wave-uniform base + lane*16
__device__ __forceinline__ void gl_lds16(const unsigned short* g, unsigned short* l)
{
    __builtin_amdgcn_global_load_lds(
        (const __attribute__((address_space(1))) void*)g,
        (__attribute__((address_space(3))) void*)l, 16, 0, 0);
}

// ---------------------------------------------------------------------------
// Fused prep: blocks [0,2048): x fp32 -> xb bf16 (8 elems/thread).
// Blocks [2048,2816): Wq/Wk/Wv fp32 [k][n] -> wqkvT bf16 [n][k] (64x64 tiles).
// ---------------------------------------------------------------------------
__global__ __launch_bounds__(256)
void prep(const float* __restrict__ x, unsigned short* __restrict__ xb,
          const float* __restrict__ Wq, const float* __restrict__ Wk,
          const float* __restrict__ Wv, unsigned short* __restrict__ wT)
{
    __shared__ unsigned short T[64][72];
    if (blockIdx.x < 2048) {
        const size_t i = ((size_t)blockIdx.x * 256 + threadIdx.x) * 8;
        float4 a = *reinterpret_cast<const float4*>(x + i);
        float4 b = *reinterpret_cast<const float4*>(x + i + 4);
        unsigned short t[8] = { f2bf(a.x), f2bf(a.y), f2bf(a.z), f2bf(a.w),
                                f2bf(b.x), f2bf(b.y), f2bf(b.z), f2bf(b.w) };
        *reinterpret_cast<uint4*>(xb + i) = *reinterpret_cast<uint4*>(t);
        return;
    }
    const int blk = blockIdx.x - 2048;
    const int z = blk >> 8, within = blk & 255;
    const float* W = (z == 0) ? Wq : (z == 1) ? Wk : Wv;
    unsigned short* dstBase = wT + (size_t)z * 1024 * 1024;
    const int k0 = (within >> 4) * 64, n0 = (within & 15) * 64;
    const int r = threadIdx.x >> 2, c0 = (threadIdx.x & 3) * 16;
    const float* src = W + (size_t)(k0 + r) * 1024 + n0 + c0;
    #pragma unroll
    for (int j = 0; j < 16; j += 4) {
        float4 f = *reinterpret_cast<const float4*>(src + j);
        T[r][c0 + j]     = f2bf(f.x);
        T[r][c0 + j + 1] = f2bf(f.y);
        T[r][c0 + j + 2] = f2bf(f.z);
        T[r][c0 + j + 3] = f2bf(f.w);
    }
    __syncthreads();
    unsigned short* dst = dstBase + (size_t)(n0 + r) * 1024 + k0 + c0;
    #pragma unroll
    for (int h = 0; h < 2; ++h) {
        unsigned short t8[8];
        #pragma unroll
        for (int j = 0; j < 8; ++j) t8[j] = T[c0 + h * 8 + j][r];
        *reinterpret_cast<uint4*>(dst + h * 8) = *reinterpret_cast<uint4*>(t8);
    }
}

// ---------------------------------------------------------------------------
// Transpose-convert (Wo): fp32 [k][n] -> bf16 [n][k].
// ---------------------------------------------------------------------------
__global__ __launch_bounds__(256)
void wconv(const float* __restrict__ W, unsigned short* __restrict__ wT)
{
    __shared__ unsigned short T[64][72];
    const int k0 = blockIdx.y * 64, n0 = blockIdx.x * 64;
    const int r = threadIdx.x >> 2, c0 = (threadIdx.x & 3) * 16;
    const float* src = W + (size_t)(k0 + r) * 1024 + n0 + c0;
    #pragma unroll
    for (int j = 0; j < 16; j += 4) {
        float4 f = *reinterpret_cast<const float4*>(src + j);
        T[r][c0 + j]     = f2bf(f.x);
        T[r][c0 + j + 1] = f2bf(f.y);
        T[r][c0 + j + 2] = f2bf(f.z);
        T[r][c0 + j + 3] = f2bf(f.w);
    }
    __syncthreads();
    unsigned short* dst = wT + (size_t)(n0 + r) * 1024 + k0 + c0;
    #pragma unroll
    for (int h = 0; h < 2; ++h) {
        unsigned short t8[8];
        #pragma unroll
        for (int j = 0; j < 8; ++j) t8[j] = T[c0 + h * 8 + j][r];
        *reinterpret_cast<uint4*>(dst + h * 8) = *reinterpret_cast<uint4*>(t8);
    }
}

// ---------------------------------------------------------------------------
// m97-style GEMM (R1-verified): C = A[4096][1024] @ BT[N][1024]^T. 128x128
// tile, BK=32, unpadded LDS, global_load_lds width-16 staging, 4 waves 2x2,
// 4x4 mfma. MODE 0: QKV routing (q/k normal, v transposed). MODE 2: fp32
// out + bias.
// ---------------------------------------------------------------------------
template <int MODE>
__global__ __launch_bounds__(256)
void gemm128(const unsigned short* __restrict__ A,
             const unsigned short* __restrict__ BT,
             void* __restrict__ C0, void* __restrict__ C1,
             void* __restrict__ C2, const float* __restrict__ bias)
{
    __shared__ unsigned short As[128 * 32];
    __shared__ unsigned short Bs[128 * 32];

    const int tid = threadIdx.x;
    const int wave = tid >> 6, lane = tid & 63, quad = lane >> 4, l16 = lane & 15;
    const int wm = wave >> 1, wn = wave & 1;
    const int mBase = blockIdx.y * 128, nBase = blockIdx.x * 128;

    f32x4 acc[4][4] = {};

    const int srow = lane >> 2, sko = (lane & 3) * 8;

    for (int kb = 0; kb < 1024; kb += 32) {
        __syncthreads();
        #pragma unroll
        for (int j = 0; j < 2; ++j) {
            const int seg = wave * 2 + j;
            gl_lds16(A  + (size_t)(mBase + seg * 16 + srow) * 1024 + kb + sko,
                     As + seg * 512);
            gl_lds16(BT + (size_t)(nBase + seg * 16 + srow) * 1024 + kb + sko,
                     Bs + seg * 512);
        }
        __syncthreads();

        bf16x8 af[4], bf[4];
        #pragma unroll
        for (int t = 0; t < 4; ++t) {
            af[t] = *reinterpret_cast<const bf16x8*>(&As[(wm * 64 + t * 16 + l16) * 32 + quad * 8]);
            bf[t] = *reinterpret_cast<const bf16x8*>(&Bs[(wn * 64 + t * 16 + l16) * 32 + quad * 8]);
        }
        #pragma unroll
        for (int ti = 0; ti < 4; ++ti)
            #pragma unroll
            for (int tj = 0; tj < 4; ++tj)
                acc[ti][tj] = __builtin_amdgcn_mfma_f32_16x16x32_bf16(
                    af[ti], bf[tj], acc[ti][tj], 0, 0, 0);
    }

    #pragma unroll
    for (int ti = 0; ti < 4; ++ti) {
        const int row0 = mBase + wm * 64 + ti * 16 + quad * 4;
        #pragma unroll
        for (int tj = 0; tj < 4; ++tj) {
            const int col = nBase + wn * 64 + tj * 16 + l16;
            if constexpr (MODE == 0) {
                if (col < 1024) {
                    unsigned short* qb = (unsigned short*)C0;
                    #pragma unroll
                    for (int i = 0; i < 4; ++i)
                        qb[(size_t)(row0 + i) * 1024 + col] = f2bf(acc[ti][tj][i]);
                } else if (col < 2048) {
                    unsigned short* kb = (unsigned short*)C1;
                    #pragma unroll
                    for (int i = 0; i < 4; ++i)
                        kb[(size_t)(row0 + i) * 1024 + col - 1024] = f2bf(acc[ti][tj][i]);
                } else {
                    unsigned short* vT = (unsigned short*)C2;
                    unsigned short t4[4] = { f2bf(acc[ti][tj][0]), f2bf(acc[ti][tj][1]),
                                             f2bf(acc[ti][tj][2]), f2bf(acc[ti][tj][3]) };
                    *reinterpret_cast<uint2*>(&vT[(size_t)(col - 2048) * 4096 + row0]) =
                        *reinterpret_cast<uint2*>(t4);
                }
            } else {
                float* out = (float*)C0;
                const float ba = bias[col];
                #pragma unroll
                for (int i = 0; i < 4; ++i)
                    out[(size_t)(row0 + i) * 1024 + col] = acc[ti][tj][i] + ba;
            }
        }
    }
}

// ---------------------------------------------------------------------------
// attn9 = attn7 + ONE change: deep staging pipeline. 3-buffer LDS rotation,
// stage(kt+2) each iteration, counted s_waitcnt vmcnt(4) + raw s_barrier
// (vmcnt(0) only at the last iteration). Everything else identical to the
// R1-verified attn7 (swapped-QK^T 32x32x16, in-register softmax via
// cvt_pk+permlane32_swap, XOR-swizzled K/V staging, triangle folding,
// LDS partial-combine epilogue).
// Correctness: per wave each stage() = exactly 4 VMEM loads -> vmcnt(4)
// retires tile kt's loads while leaving tile kt+1's in flight. Buffer
// (kt+2)%3 overwritten at iter kt was last read at iter kt-1; every
// ds_read's consuming MFMA (behind its lgkmcnt wait) issues before that
// wave reaches iter kt's barrier, so the write-after-read is fenced by the
// barrier. Q-frag loads are pinned pre-loop so the in-loop vmcnt immediates
// count only staging loads.
// ---------------------------------------------------------------------------
__global__ __launch_bounds__(256, 2)
void attn9(const unsigned short* __restrict__ q,
           const unsigned short* __restrict__ k,
           const unsigned short* __restrict__ vT,
           unsigned short* __restrict__ ctx)
{
    __shared__ unsigned short Ks[3][64 * 64];  // [buf][key][d], 16B units XOR-swizzled
    __shared__ unsigned short Vs[3][64 * 64];  // [buf][d][key], 16B units XOR-swizzled
    __shared__ float Lt[8 * 64];               // [wave][tile][lane] l partials

    const int tid  = threadIdx.x;
    const int wave = tid >> 6, lane = tid & 63;
    const int q32 = lane & 31, hi = lane >> 5;
    const int slice = wave & 1;                // 32-row q slice within 64-row macro tile
    const int ks    = wave >> 1;               // 32-key subtile within 64-key staged tile
    const int j  = blockIdx.x;                 // 0..15 pair index
    const int bh = blockIdx.y;
    const int b = bh >> 4, h = bh & 15;
    const int tokBase = b * 2048;
    const int colBase = h * 64;
    const int qtA = 31 - j, qtB = j;
    const int qloA = qtA * 64 + slice * 32;    // local (per-batch) q-row base of this wave
    const int qloB = qtB * 64 + slice * 32;

    // Q fragments (QK^T B-operand: lane col q = lane&31, d = c*16 + hi*8 + 0..7)
    bf16x8 aqA[4], aqB[4];
    {
        const unsigned short* ra = q + (size_t)(tokBase + qloA + q32) * 1024 + colBase + hi * 8;
        const unsigned short* rb = q + (size_t)(tokBase + qloB + q32) * 1024 + colBase + hi * 8;
        #pragma unroll
        for (int c = 0; c < 4; ++c) {
            aqA[c] = *reinterpret_cast<const bf16x8*>(ra + c * 16);
            aqB[c] = *reinterpret_cast<const bf16x8*>(rb + c * 16);
        }
    }
    // Pin Q here: the scoreboard wait for these 8 loads lands pre-loop, so the
    // in-loop vmcnt immediates only ever count staging loads.
    #pragma unroll
    for (int c = 0; c < 4; ++c)
        asm volatile("" :: "v"(aqA[c]), "v"(aqB[c]));

    f32x16 oA[2] = {}, oB[2] = {};             // [d-half], 32q x 32d each
    float lsA = 0.0f, lsB = 0.0f;

    // Staging: K tile = 64 key-rows x 64 d (128B rows, 8 x 16B units);
    // V tile = 64 d-rows x 64 keys. Linear LDS dest (slot s = r*8 + pu),
    // source pre-swizzled so content at unit pu is logical unit pu ^ (r&7).
    const int s0 = (wave * 2 + 0) * 64 + lane;
    const int s1 = (wave * 2 + 1) * 64 + lane;
    const int r0 = s0 >> 3, sw0 = (s0 & 7) ^ (r0 & 7);
    const int r1 = s1 >> 3, sw1 = (s1 & 7) ^ (r1 & 7);
    const size_t kOff0 = (size_t)r0 * 1024 + colBase + sw0 * 8;
    const size_t kOff1 = (size_t)r1 * 1024 + colBase + sw1 * 8;
    const size_t vOff0 = (size_t)(colBase + r0) * 4096 + sw0 * 8;
    const size_t vOff1 = (size_t)(colBase + r1) * 4096 + sw1 * 8;

    auto stage = [&](int tok0, int buf) {      // exactly 4 VMEM loads per wave
        gl_lds16(k  + (size_t)tok0 * 1024 + kOff0, &Ks[buf][(wave * 2 + 0) * 512]);
        gl_lds16(k  + (size_t)tok0 * 1024 + kOff1, &Ks[buf][(wave * 2 + 1) * 512]);
        gl_lds16(vT + vOff0 + tok0,                &Vs[buf][(wave * 2 + 0) * 512]);
        gl_lds16(vT + vOff1 + tok0,                &Vs[buf][(wave * 2 + 1) * 512]);
    };

    bf16x8 ak[4];       // K frags (shared by tiles A and B)
    bf16x8 bv[2][2];    // V frags [k-chunk][d-half] (shared by A and B)

    // One (q,k) 32x32 tile: swapped QK^T -> in-register softmax -> PV.
    auto tile = [&](const bf16x8 (&aq)[4], f32x16 (&o)[2], float& ls,
                    int qlo, int klo) {
        if (klo > qlo + 31) return;                      // fully masked (wave-uniform)
        f32x16 sc = (f32x16)0.0f;
        #pragma unroll
        for (int c = 0; c < 4; ++c)
            sc = __builtin_amdgcn_mfma_f32_32x32x16_bf16(ak[c], aq[c], sc, 0, 0, 0);
        // lane holds S[k = klo + krow(r,hi)][q = qlo + q32]
        float p[16];
        #pragma unroll
        for (int r = 0; r < 16; ++r) p[r] = __expf(sc[r] * 0.125f);
        if (klo + 31 > qlo) {                            // diagonal block: causal mask
            #pragma unroll
            for (int r = 0; r < 16; ++r) {
                const int krow = (r & 3) + 8 * (r >> 2) + 4 * hi;
                if (klo + krow > qlo + q32) p[r] = 0.0f;
            }
        }
        #pragma unroll
        for (int r = 0; r < 16; ++r) ls += p[r];
        // pack consecutive-k pairs to bf16 (8 words)
        unsigned int pk[8];
        #pragma unroll
        for (int i = 0; i < 8; ++i)
            asm("v_cvt_pk_bf16_f32 %0, %1, %2"
                : "=v"(pk[i]) : "v"(p[2 * i]), "v"(p[2 * i + 1]));
        // build PV A-frags: swap(pk[i], pk[i+2]) fills words i and i+2 of both halves
        #pragma unroll
        for (int kc = 0; kc < 2; ++kc) {
            unsigned int x0 = pk[kc * 4 + 0], y0 = pk[kc * 4 + 2];
            unsigned int x1 = pk[kc * 4 + 1], y1 = pk[kc * 4 + 3];
            asm("v_permlane32_swap_b32 %0, %1" : "+v"(x0), "+v"(y0));
            asm("v_permlane32_swap_b32 %0, %1" : "+v"(x1), "+v"(y1));
            const u32x4 wv = { x0, x1, y0, y1 };
            const bf16x8 pa = __builtin_bit_cast(bf16x8, wv);
            #pragma unroll
            for (int dh = 0; dh < 2; ++dh)
                o[dh] = __builtin_amdgcn_mfma_f32_32x32x16_bf16(pa, bv[kc][dh], o[dh], 0, 0, 0);
        }
    };

    const int nkt = qtA + 1;                   // 64-key tiles; >= 17 always
    stage(tokBase, 0);                         // prologue: 2 tiles in flight
    stage(tokBase + 64, 1);

    int cur = 0;                               // buffer holding tile kt
    const int krowK = ks * 32 + q32;           // K-frag LDS row for this wave
    for (int kt = 0; kt < nkt; ++kt) {
        // retire tile kt's 4 loads; leave tile kt+1's 4 in flight (T4)
        if (kt + 1 < nkt) asm volatile("s_waitcnt vmcnt(4)" ::: "memory");
        else              asm volatile("s_waitcnt vmcnt(0)" ::: "memory");
        __builtin_amdgcn_s_barrier();
        asm volatile("" ::: "memory");

        const int stg = (cur == 0) ? 2 : cur - 1;        // (cur+2)%3
        if (kt + 2 < nkt)
            stage(tokBase + (kt + 2) * 64, stg);         // lands ~2 iters out

        const unsigned short* KsB = Ks[cur];
        const unsigned short* VsB = Vs[cur];
        #pragma unroll
        for (int c = 0; c < 4; ++c) {
            const int u = c * 2 + hi;
            ak[c] = *reinterpret_cast<const bf16x8*>(
                &KsB[krowK * 64 + ((u ^ (krowK & 7)) * 8)]);
        }
        #pragma unroll
        for (int kc = 0; kc < 2; ++kc)
            #pragma unroll
            for (int dh = 0; dh < 2; ++dh) {
                const int vrow = dh * 32 + q32;
                const int u = ks * 4 + kc * 2 + hi;
                bv[kc][dh] = *reinterpret_cast<const bf16x8*>(
                    &VsB[vrow * 64 + ((u ^ (vrow & 7)) * 8)]);
            }
        const int klo = kt * 64 + ks * 32;
        tile(aqA, oA, lsA, qloA, klo);
        tile(aqB, oB, lsB, qloB, klo);
        cur = (cur == 2) ? 0 : cur + 1;
    }

    // ---- epilogue: combine the two k-subtile partials per q-slice, normalize
    float* Obuf = reinterpret_cast<float*>(&Ks[0][0]);   // 2 slots x 8KB (overlay)

    __syncthreads();                           // all compute reads done; overlay safe
    Lt[(wave * 2 + 0) * 64 + lane] = lsA;
    Lt[(wave * 2 + 1) * 64 + lane] = lsB;

    auto writePartial = [&](const f32x16 (&o)[2]) {
        float* slot = Obuf + slice * 2048;
        #pragma unroll
        for (int r = 0; r < 16; ++r) {
            const int row = (r & 3) + 8 * (r >> 2) + 4 * hi;
            #pragma unroll
            for (int dh = 0; dh < 2; ++dh)
                slot[row * 64 + dh * 32 + q32] = o[dh][r];
        }
    };
    auto finalize = [&](int t, int qt, const f32x16 (&o)[2]) {
        const float lf = Lt[(slice * 2 + t) * 64 + q32]
                       + Lt[(slice * 2 + t) * 64 + 32 + q32]
                       + Lt[((slice + 2) * 2 + t) * 64 + q32]
                       + Lt[((slice + 2) * 2 + t) * 64 + 32 + q32];
        const float inv = 1.0f / lf;
        const float* slot = Obuf + slice * 2048;
        #pragma unroll
        for (int r = 0; r < 16; ++r) {
            const int row = (r & 3) + 8 * (r >> 2) + 4 * hi;
            const float invr = __shfl(inv, row);
            const size_t gr = (size_t)(tokBase + qt * 64 + slice * 32 + row) * 1024 + colBase;
            #pragma unroll
            for (int dh = 0; dh < 2; ++dh)
                ctx[gr + dh * 32 + q32] =
                    f2bf((o[dh][r] + slot[row * 64 + dh * 32 + q32]) * invr);
        }
    };

    if (ks == 1) writePartial(oA);             // waves 2,3 publish A partials
    __syncthreads();
    if (ks == 0) finalize(0, qtA, oA);         // waves 0,1 finalize tile A
    __syncthreads();
    if (ks == 0) writePartial(oB);             // waves 0,1 publish B partials
    __syncthreads();
    if (ks == 1) finalize(1, qtB, oB);         // waves 2,3 finalize tile B
}

// ---------------------------------------------------------------------------
extern "C" void kernel_launch(void* const* d_in, const int* in_sizes, int n_in,
                              void* d_out, int out_size, void* d_ws, size_t ws_size,
                              hipStream_t stream)
{
    const float* x  = (const float*)d_in[0];   // [4096,1024] fp32
    const float* Wq = (const float*)d_in[1];
    const float* Wk = (const float*)d_in[2];
    const float* Wv = (const float*)d_in[3];
    const float* Wo = (const float*)d_in[4];
    const float* bo = (const float*)d_in[5];
    float* out = (float*)d_out;

    // ws (32 MB): xb -> ctx after gemm_qkv; kb -> woT after attn.
    // d_out doubles as wqkvT scratch until gemm_out overwrites it.
    unsigned short* xb     = (unsigned short*)d_ws;           // 8 MB -> ctx
    unsigned short* qb     = xb + (size_t)4096 * 1024;        // 8 MB
    unsigned short* kb     = qb + (size_t)4096 * 1024;        // 8 MB -> woT
    unsigned short* vT     = kb + (size_t)4096 * 1024;        // 8 MB [1024][4096]
    unsigned short* ctx    = xb;
    unsigned short* wqkvT  = (unsigned short*)d_out;          // 6.3 MB scratch
    unsigned short* woT    = kb;

    prep<<<2816, 256, 0, stream>>>(x, xb, Wq, Wk, Wv, wqkvT);

    gemm128<0><<<dim3(24, 32), 256, 0, stream>>>(xb, wqkvT, qb, kb, vT, nullptr);

    attn9<<<dim3(16, 32), 256, 0, stream>>>(qb, kb, vT, ctx);

    wconv<<<dim3(16, 16), 256, 0, stream>>>(Wo, woT);

    gemm128<2><<<dim3(8, 32), 256, 0, stream>>>(ctx, woT, out, nullptr, nullptr, bo);
}